// Round 9
// baseline (50948.273 us; speedup 1.0000x reference)
//
#include <hip/hip_runtime.h>
#include <stdint.h>

#define TSTEPS 100
#define BATCH  512
#define NH     256
#define NS     128

__device__ __forceinline__ uint32_t rotl32(uint32_t x, int r) {
  return (x << r) | (x >> (32 - r));
}

// Threefry-2x32-20, exactly as jax/_src/prng.py
__device__ __forceinline__ void tf2x32(uint32_t k0, uint32_t k1,
                                       uint32_t c0, uint32_t c1,
                                       uint32_t& o0, uint32_t& o1) {
  const uint32_t ks2 = k0 ^ k1 ^ 0x1BD11BDAu;
  uint32_t x0 = c0 + k0, x1 = c1 + k1;
#define TFR(r) { x0 += x1; x1 = rotl32(x1, r); x1 ^= x0; }
  TFR(13) TFR(15) TFR(26) TFR(6)
  x0 += k1;  x1 += ks2 + 1u;
  TFR(17) TFR(29) TFR(16) TFR(24)
  x0 += ks2; x1 += k0 + 2u;
  TFR(13) TFR(15) TFR(26) TFR(6)
  x0 += k0;  x1 += k1 + 3u;
  TFR(17) TFR(29) TFR(16) TFR(24)
  x0 += k1;  x1 += ks2 + 4u;
  TFR(13) TFR(15) TFR(26) TFR(6)
  x0 += ks2; x1 += k0 + 5u;
#undef TFR
  o0 = x0; o1 = x1;
}

// XLA:CPU GenerateVF32Log (Cephes port, FMA form). Inputs in (0,1], normal.
__device__ __forceinline__ float xla_vf32_log(float a) {
  uint32_t bits = __float_as_uint(a);
  float e = __fadd_rn((float)((int)(bits >> 23) - 127), 1.0f);
  float x = __uint_as_float((bits & 0x007FFFFFu) | 0x3F000000u);
  const bool mask = x < 0.707106781186547524f;
  float tmp = mask ? x : 0.0f;
  x = __fsub_rn(x, 1.0f);
  e = mask ? __fsub_rn(e, 1.0f) : e;
  x = __fadd_rn(x, tmp);
  float z = __fmul_rn(x, x);
  float y = 7.0376836292e-2f;
  y = __fmaf_rn(y, x, -1.1514610310e-1f);
  y = __fmaf_rn(y, x, 1.1676998740e-1f);
  y = __fmaf_rn(y, x, -1.2420140846e-1f);
  y = __fmaf_rn(y, x, 1.4249322787e-1f);
  y = __fmaf_rn(y, x, -1.6668057665e-1f);
  y = __fmaf_rn(y, x, 2.0000714765e-1f);
  y = __fmaf_rn(y, x, -2.4999993993e-1f);
  y = __fmaf_rn(y, x, 3.3333331174e-1f);
  y = __fmul_rn(y, x);
  y = __fmul_rn(y, z);
  y = __fmaf_rn(e, -2.12194440e-4f, y);
  y = __fmaf_rn(-0.5f, z, y);
  x = __fadd_rn(x, y);
  x = __fmaf_rn(e, 0.693359375f, x);
  return x;
}

// sqrt(2)*erfinv(u): chlo erf_inv f32 (Giles) + EmitLog1p, FMA-contracted.
__device__ __forceinline__ float xla_sqrt2_erfinv(float u) {
  float nxx = -__fmul_rn(u, u);
  float w;
  if (fabsf(nxx) < 1e-4f) {
    w = -__fmul_rn(__fmaf_rn(-0.5f, nxx, 1.0f), nxx);
  } else {
    w = -xla_vf32_log(__fadd_rn(nxx, 1.0f));
  }
  float p;
  if (w < 5.0f) {
    float t = __fsub_rn(w, 2.5f);
    p = 2.81022636e-08f;
    p = __fmaf_rn(p, t, 3.43273939e-07f);
    p = __fmaf_rn(p, t, -3.5233877e-06f);
    p = __fmaf_rn(p, t, -4.39150654e-06f);
    p = __fmaf_rn(p, t, 0.00021858087f);
    p = __fmaf_rn(p, t, -0.00125372503f);
    p = __fmaf_rn(p, t, -0.00417768164f);
    p = __fmaf_rn(p, t, 0.246640727f);
    p = __fmaf_rn(p, t, 1.50140941f);
  } else {
    float t = __fsub_rn(__fsqrt_rn(w), 3.0f);
    p = -0.000200214257f;
    p = __fmaf_rn(p, t, 0.000100950558f);
    p = __fmaf_rn(p, t, 0.00134934322f);
    p = __fmaf_rn(p, t, -0.00367342844f);
    p = __fmaf_rn(p, t, 0.00573950773f);
    p = __fmaf_rn(p, t, -0.0076224613f);
    p = __fmaf_rn(p, t, 0.00943887047f);
    p = __fmaf_rn(p, t, 1.00167406f);
    p = __fmaf_rn(p, t, 2.83297682f);
  }
  return __fmul_rn((float)1.4142135623730951, __fmul_rn(p, u));
}

// jax.random.normal element j under key (k0,k1), threefry-partitionable.
__device__ __forceinline__ float jax_normal(uint32_t k0, uint32_t k1, uint32_t j) {
  uint32_t o0, o1;
  tf2x32(k0, k1, 0u, j, o0, o1);
  const uint32_t bits = o0 ^ o1;
  float f = __fsub_rn(__uint_as_float((bits >> 9) | 0x3f800000u), 1.0f);
  const float LO = -0.99999994f;
  float u = __fmaf_rn(f, 2.0f, LO);
  u = fmaxf(LO, u);
  return xla_sqrt2_erfinv(u);
}

// Pack W[K][256] -> P[k/4][n][4]; optionally zero diagonal (rec masks).
__global__ void pack_w(const float* __restrict__ src, float* __restrict__ dst,
                       int K, int zero_diag) {
  int tid = blockIdx.x * 256 + threadIdx.x;
  if (tid >= K * NH) return;
  int k = tid >> 8, n = tid & 255;
  float v = src[tid];
  if (zero_diag && k == n) v = 0.f;
  dst[(((k >> 2) * NH) + n) * 4 + (k & 3)] = v;
}

// Precompute all scaled noise draws: NZ[((t*5+d)*BATCH+b)*NH+n].
__global__ __launch_bounds__(256)
void gen_noise(float* __restrict__ NZ) {
  uint32_t idx = blockIdx.x * 256u + threadIdx.x;
  uint32_t j = idx & 131071u;          // b*NH + n
  uint32_t td = idx >> 17;             // t*5 + d  (< 500)
  uint32_t t = td / 5u, d = td - 5u * t;
  uint32_t fk0, fk1, k0, k1;
  tf2x32(0u, 42u, 0u, t, fk0, fk1);
  tf2x32(fk0, fk1, 0u, d, k0, k1);
  float z = jax_normal(k0, k1, j);
  float scale = (d >= 3u) ? 0.01f : 0.02f;
  NZ[idx] = __fmul_rn(scale, z);
}

// ============ deep-pipelined dots ============
// Weight loads for group g+1 are issued BEFORE the FMAs of group g
// (ping-pong register buffers). Only LOADS are reordered; each
// accumulator's FMA chain stays strictly k-ascending -> bit-exact.

// two matrices (independent k-offsets o0/o1), one row each, groups of 8 k4
template<int NG>
__device__ __forceinline__ void pipe2(const float4* __restrict__ P0,
                                      const float* __restrict__ X0, int o0,
                                      const float4* __restrict__ P1,
                                      const float* __restrict__ X1, int o1,
                                      int n, float& r0, float& r1) {
  float4 w0[2][8], w1[2][8];
  float a0 = r0, a1 = r1;
  #pragma unroll
  for (int i = 0; i < 8; ++i) {
    w0[0][i] = P0[(o0 + i) * NH + n];
    w1[0][i] = P1[(o1 + i) * NH + n];
  }
  #pragma unroll
  for (int g = 0; g < NG; ++g) {
    const int cur = g & 1, nxt = cur ^ 1;
    if (g + 1 < NG) {
      #pragma unroll
      for (int i = 0; i < 8; ++i) {
        w0[nxt][i] = P0[(o0 + (g + 1) * 8 + i) * NH + n];
        w1[nxt][i] = P1[(o1 + (g + 1) * 8 + i) * NH + n];
      }
    }
    #pragma unroll
    for (int i = 0; i < 8; ++i) {
      float4 x0 = *(const float4*)&X0[(o0 + g * 8 + i) * 4];
      float4 x1 = *(const float4*)&X1[(o1 + g * 8 + i) * 4];
      float4 u = w0[cur][i], v = w1[cur][i];
      a0 = __fmaf_rn(x0.x, u.x, a0); a1 = __fmaf_rn(x1.x, v.x, a1);
      a0 = __fmaf_rn(x0.y, u.y, a0); a1 = __fmaf_rn(x1.y, v.y, a1);
      a0 = __fmaf_rn(x0.z, u.z, a0); a1 = __fmaf_rn(x1.z, v.z, a1);
      a0 = __fmaf_rn(x0.w, u.w, a0); a1 = __fmaf_rn(x1.w, v.w, a1);
    }
  }
  r0 = a0; r1 = a1;
}

// single matrix, groups of 16 k4 (deeper to keep latency hidden)
template<int NG>
__device__ __forceinline__ void pipe1(const float4* __restrict__ P,
                                      const float* __restrict__ X, int o,
                                      int n, float& r) {
  float4 w[2][16];
  float a = r;
  #pragma unroll
  for (int i = 0; i < 16; ++i) w[0][i] = P[(o + i) * NH + n];
  #pragma unroll
  for (int g = 0; g < NG; ++g) {
    const int cur = g & 1, nxt = cur ^ 1;
    if (g + 1 < NG) {
      #pragma unroll
      for (int i = 0; i < 16; ++i)
        w[nxt][i] = P[(o + (g + 1) * 16 + i) * NH + n];
    }
    #pragma unroll
    for (int i = 0; i < 16; ++i) {
      float4 x = *(const float4*)&X[(o + g * 16 + i) * 4];
      float4 u = w[cur][i];
      a = __fmaf_rn(x.x, u.x, a);
      a = __fmaf_rn(x.y, u.y, a);
      a = __fmaf_rn(x.z, u.z, a);
      a = __fmaf_rn(x.w, u.w, a);
    }
  }
  r = a;
}

__global__ __launch_bounds__(NH)
void wm_fast3(const float* __restrict__ sensory,
              const float4* __restrict__ pred0p, const float4* __restrict__ pred1p,
              const float4* __restrict__ p2r0p,  const float4* __restrict__ rec0p,
              const float4* __restrict__ ff0p,   const float4* __restrict__ p2r1p,
              const float4* __restrict__ ff1p,   const float4* __restrict__ rec1p,
              const float4* __restrict__ ff2p,   const float4* __restrict__ rec2p,
              const float* __restrict__ NZ,
              float* __restrict__ out) {
  const int b = blockIdx.x;
  const int n = threadIdx.x;

  __shared__ __align__(16) float last[2][3][NH];
  __shared__ __align__(16) float psp0[NH];
  __shared__ __align__(16) float psp1[NH];
  __shared__ __align__(16) float sens[NS];
  __shared__ __align__(16) float errsq[3][NH];
  __shared__ float evsum[3];

  for (int i = 0; i < 3; ++i) { last[0][i][n] = 0.f; last[1][i][n] = 0.f; }

  float v0 = 0.f, v1 = 0.f, v2 = 0.f, pv0 = 0.f, pv1 = 0.f;
  float prec0 = 1.f, prec1 = 1.f, prec2 = 1.f;
  const float DM = (float)0.951229424500714009;  // f32(exp(-1/20))
  const float DP = (float)0.980198673306755250;  // f32(exp(-1/50))

  __syncthreads();

  for (int t = 0; t < TSTEPS; ++t) {
    const int p = t & 1, q = p ^ 1;
    const size_t nb = ((size_t)t * 5 * BATCH + b) * NH + n;  // draw 0 offset

    // ---- A: fused pred-LIF 0 & 1 ----
    if (n < NS) sens[n] = sensory[((size_t)t * BATCH + b) * NS + n];
    {
      float pn0 = NZ[nb + (size_t)3 * BATCH * NH];
      float pn1 = NZ[nb + (size_t)4 * BATCH * NH];
      float acc0 = 0.f, acc1 = 0.f;
      pipe2<8>(pred0p, last[p][1], 0, pred1p, last[p][2], 0, n, acc0, acc1);
      pv0 = __fadd_rn(__fmaf_rn(DP, pv0, acc0), pn0);
      bool s0 = (pv0 >= 1.0f);
      psp0[n] = s0 ? 1.f : 0.f;
      pv0 = s0 ? 0.f : pv0;
      pv1 = __fadd_rn(__fmaf_rn(DP, pv1, acc1), pn1);
      bool s1 = (pv1 >= 1.0f);
      psp1[n] = s1 ? 1.f : 0.f;
      pv1 = s1 ? 0.f : pv1;
    }
    __syncthreads();

    // ---- B: layer 0 ----
    {
      float noi = NZ[nb];
      float inp = 0.f, rc = 0.f, pr = 0.f;
      pipe2<4>(ff0p, sens, 0, rec0p, last[p][0], 0, n, inp, rc);
      pipe2<4>(rec0p, last[p][0], 32, p2r0p, psp0, 0, n, rc, pr);
      pipe1<2>(p2r0p, psp0, 32, n, pr);
      float err = __fsub_rn(inp, pr);
      out[(((size_t)t * 3 + 0) * BATCH + b) * NH + n] = err;
      errsq[0][n] = __fmul_rn(err, err);
      float m1  = __fmul_rn(err, 0.5f);
      float tot = __fadd_rn(__fmaf_rn(m1, prec0, pr), rc);
      v0 = __fadd_rn(__fmaf_rn(DM, v0, tot), noi);
      bool s = (v0 >= 1.0f);
      last[q][0][n] = s ? 1.f : 0.f;
      v0 = s ? 0.f : v0;
    }
    __syncthreads();

    // ---- D: layer 1 (input: NEW layer-0 spikes; pred from psp1) ----
    {
      float noi = NZ[nb + (size_t)1 * BATCH * NH];
      float inp = 0.f, rc = 0.f, pr = 0.f;
      pipe2<8>(ff1p, last[q][0], 0, rec1p, last[p][1], 0, n, inp, rc);
      pipe1<4>(p2r1p, psp1, 0, n, pr);
      float err = __fsub_rn(inp, pr);
      out[(((size_t)t * 3 + 1) * BATCH + b) * NH + n] = err;
      errsq[1][n] = __fmul_rn(err, err);
      float m1  = __fmul_rn(err, 0.5f);
      float tot = __fadd_rn(__fmaf_rn(m1, prec1, pr), rc);
      v1 = __fadd_rn(__fmaf_rn(DM, v1, tot), noi);
      bool s = (v1 >= 1.0f);
      last[q][1][n] = s ? 1.f : 0.f;
      v1 = s ? 0.f : v1;
    }
    __syncthreads();

    // ---- E: layer 2 (no prediction) ----
    {
      float noi = NZ[nb + (size_t)2 * BATCH * NH];
      float inp = 0.f, rc = 0.f;
      pipe2<8>(ff2p, last[q][1], 0, rec2p, last[p][2], 0, n, inp, rc);
      float err = inp;
      out[(((size_t)t * 3 + 2) * BATCH + b) * NH + n] = err;
      errsq[2][n] = __fmul_rn(err, err);
      float m1  = __fmul_rn(err, 0.5f);
      float tot = __fadd_rn(__fmaf_rn(m1, prec2, 0.0f), rc);
      v2 = __fadd_rn(__fmaf_rn(DM, v2, tot), noi);
      bool s = (v2 >= 1.0f);
      last[q][2][n] = s ? 1.f : 0.f;
      v2 = s ? 0.f : v2;
    }
    __syncthreads();

    // ---- F: strict sequential err^2 sums (lane 0 of waves 0..2) ----
    if (((n & 63) == 0) && n < 192) {
      const float4* s4 = reinterpret_cast<const float4*>(errsq[n >> 6]);
      float acc = 0.f;
      #pragma unroll 16
      for (int k4 = 0; k4 < 64; ++k4) {
        float4 v = s4[k4];
        acc = __fadd_rn(acc, v.x); acc = __fadd_rn(acc, v.y);
        acc = __fadd_rn(acc, v.z); acc = __fadd_rn(acc, v.w);
      }
      evsum[n >> 6] = acc;
    }
    __syncthreads();

    // ---- G: precision EMA ----
    {
      float ev0 = __fadd_rn(__fmul_rn(evsum[0], 0.00390625f), 1e-6f);
      float ev1 = __fadd_rn(__fmul_rn(evsum[1], 0.00390625f), 1e-6f);
      float ev2 = __fadd_rn(__fmul_rn(evsum[2], 0.00390625f), 1e-6f);
      prec0 = __fmaf_rn(0.98f, prec0, __fmul_rn(0.02f, 1.0f / ev0));
      prec1 = __fmaf_rn(0.98f, prec1, __fmul_rn(0.02f, 1.0f / ev1));
      prec2 = __fmaf_rn(0.98f, prec2, __fmul_rn(0.02f, 1.0f / ev2));
    }
  }
}

// ======================= fallback (verified R5 kernel) =======================
__device__ __forceinline__ float dot_lds(const float* __restrict__ a,
                                         const float* __restrict__ W,
                                         int n, int K) {
  float acc = 0.f;
  #pragma unroll 8
  for (int k = 0; k < K; ++k)
    acc = __fmaf_rn(a[k], W[k * NH + n], acc);
  return acc;
}

__device__ __forceinline__ float dot_rec(const float* __restrict__ a,
                                         const float* __restrict__ W, int n) {
  float acc = 0.f;
  #pragma unroll 8
  for (int k = 0; k < NH; ++k) {
    float w = (k == n) ? 0.f : W[k * NH + n];
    acc = __fmaf_rn(a[k], w, acc);
  }
  return acc;
}

__global__ __launch_bounds__(NH)
void wm_kernel_mono(const float* __restrict__ sensory,
                    const float* __restrict__ ff0, const float* __restrict__ ff1,
                    const float* __restrict__ ff2,
                    const float* __restrict__ rec0, const float* __restrict__ rec1,
                    const float* __restrict__ rec2,
                    const float* __restrict__ pred0, const float* __restrict__ pred1,
                    const float* __restrict__ p2r0, const float* __restrict__ p2r1,
                    float* __restrict__ out) {
  const int b = blockIdx.x;
  const int n = threadIdx.x;

  __shared__ float last[2][3][NH];
  __shared__ float psp[NH];
  __shared__ float sens[NS];
  __shared__ float errsq[3][NH];
  __shared__ float evsum[3];
  __shared__ uint32_t keys[TSTEPS][5][2];

  if (n < TSTEPS) {
    uint32_t fk0, fk1;
    tf2x32(0u, 42u, 0u, (uint32_t)n, fk0, fk1);
    #pragma unroll
    for (int i = 0; i < 5; ++i) {
      uint32_t s0, s1;
      tf2x32(fk0, fk1, 0u, (uint32_t)i, s0, s1);
      keys[n][i][0] = s0; keys[n][i][1] = s1;
    }
  }
  for (int i = 0; i < 3; ++i) { last[0][i][n] = 0.f; last[1][i][n] = 0.f; }

  float v0 = 0.f, v1 = 0.f, v2 = 0.f, pv0 = 0.f, pv1 = 0.f;
  float prec0 = 1.f, prec1 = 1.f, prec2 = 1.f;
  const float DM = (float)0.951229424500714009;
  const float DP = (float)0.980198673306755250;
  const uint32_t j = (uint32_t)(b * NH + n);

  __syncthreads();

  for (int t = 0; t < TSTEPS; ++t) {
    const int p = t & 1, q = p ^ 1;

    if (n < NS) sens[n] = sensory[((size_t)t * BATCH + b) * NS + n];
    {
      float acc = dot_lds(last[p][1], pred0, n, NH);
      float pn = __fmul_rn(0.01f, jax_normal(keys[t][3][0], keys[t][3][1], j));
      pv0 = __fadd_rn(__fmaf_rn(DP, pv0, acc), pn);
      bool s = (pv0 >= 1.0f);
      psp[n] = s ? 1.f : 0.f;
      pv0 = s ? 0.f : pv0;
    }
    __syncthreads();

    {
      float pr  = dot_lds(psp, p2r0, n, NH);
      float inp = dot_lds(sens, ff0, n, NS);
      float rc  = dot_rec(last[p][0], rec0, n);
      float err = __fsub_rn(inp, pr);
      out[(((size_t)t * 3 + 0) * BATCH + b) * NH + n] = err;
      errsq[0][n] = __fmul_rn(err, err);
      float m1  = __fmul_rn(err, 0.5f);
      float tot = __fadd_rn(__fmaf_rn(m1, prec0, pr), rc);
      float noi = __fmul_rn(0.02f, jax_normal(keys[t][0][0], keys[t][0][1], j));
      v0 = __fadd_rn(__fmaf_rn(DM, v0, tot), noi);
      bool s = (v0 >= 1.0f);
      last[q][0][n] = s ? 1.f : 0.f;
      v0 = s ? 0.f : v0;
    }
    __syncthreads();

    {
      float acc = dot_lds(last[p][2], pred1, n, NH);
      float pn = __fmul_rn(0.01f, jax_normal(keys[t][4][0], keys[t][4][1], j));
      pv1 = __fadd_rn(__fmaf_rn(DP, pv1, acc), pn);
      bool s = (pv1 >= 1.0f);
      psp[n] = s ? 1.f : 0.f;
      pv1 = s ? 0.f : pv1;
    }
    __syncthreads();

    {
      float pr  = dot_lds(psp, p2r1, n, NH);
      float inp = dot_lds(last[q][0], ff1, n, NH);
      float rc  = dot_rec(last[p][1], rec1, n);
      float err = __fsub_rn(inp, pr);
      out[(((size_t)t * 3 + 1) * BATCH + b) * NH + n] = err;
      errsq[1][n] = __fmul_rn(err, err);
      float m1  = __fmul_rn(err, 0.5f);
      float tot = __fadd_rn(__fmaf_rn(m1, prec1, pr), rc);
      float noi = __fmul_rn(0.02f, jax_normal(keys[t][1][0], keys[t][1][1], j));
      v1 = __fadd_rn(__fmaf_rn(DM, v1, tot), noi);
      bool s = (v1 >= 1.0f);
      last[q][1][n] = s ? 1.f : 0.f;
      v1 = s ? 0.f : v1;
    }
    __syncthreads();

    {
      float inp = dot_lds(last[q][1], ff2, n, NH);
      float rc  = dot_rec(last[p][2], rec2, n);
      float err = inp;
      out[(((size_t)t * 3 + 2) * BATCH + b) * NH + n] = err;
      errsq[2][n] = __fmul_rn(err, err);
      float m1  = __fmul_rn(err, 0.5f);
      float tot = __fadd_rn(__fmaf_rn(m1, prec2, 0.0f), rc);
      float noi = __fmul_rn(0.02f, jax_normal(keys[t][2][0], keys[t][2][1], j));
      v2 = __fadd_rn(__fmaf_rn(DM, v2, tot), noi);
      bool s = (v2 >= 1.0f);
      last[q][2][n] = s ? 1.f : 0.f;
      v2 = s ? 0.f : v2;
    }
    __syncthreads();

    if (((n & 63) == 0) && n < 192) {
      const float* s = errsq[n >> 6];
      float acc = 0.f;
      #pragma unroll 32
      for (int k = 0; k < NH; ++k) acc = __fadd_rn(acc, s[k]);
      evsum[n >> 6] = acc;
    }
    __syncthreads();

    {
      float ev0 = __fadd_rn(__fmul_rn(evsum[0], 0.00390625f), 1e-6f);
      float ev1 = __fadd_rn(__fmul_rn(evsum[1], 0.00390625f), 1e-6f);
      float ev2 = __fadd_rn(__fmul_rn(evsum[2], 0.00390625f), 1e-6f);
      prec0 = __fmaf_rn(0.98f, prec0, __fmul_rn(0.02f, 1.0f / ev0));
      prec1 = __fmaf_rn(0.98f, prec1, __fmul_rn(0.02f, 1.0f / ev1));
      prec2 = __fmaf_rn(0.98f, prec2, __fmul_rn(0.02f, 1.0f / ev2));
    }
  }
}

extern "C" void kernel_launch(void* const* d_in, const int* in_sizes, int n_in,
                              void* d_out, int out_size, void* d_ws, size_t ws_size,
                              hipStream_t stream) {
  (void)in_sizes; (void)n_in; (void)out_size;
  const float* sensory = (const float*)d_in[0];
  const float* ff0  = (const float*)d_in[1];
  const float* ff1  = (const float*)d_in[2];
  const float* ff2  = (const float*)d_in[3];
  const float* rec0 = (const float*)d_in[4];
  const float* rec1 = (const float*)d_in[5];
  const float* rec2 = (const float*)d_in[6];
  const float* pred0 = (const float*)d_in[7];
  const float* pred1 = (const float*)d_in[8];
  const float* p2r0 = (const float*)d_in[9];
  const float* p2r1 = (const float*)d_in[10];
  float* out = (float*)d_out;

  // ws layout (floats): packed weights then noise.
  const size_t OFF_PRED0 = 0, OFF_PRED1 = 65536, OFF_P2R0 = 131072,
               OFF_REC0 = 196608, OFF_FF0 = 262144, OFF_P2R1 = 294912,
               OFF_FF1 = 360448, OFF_REC1 = 425984, OFF_FF2 = 491520,
               OFF_REC2 = 557056, OFF_NZ = 655360;
  const size_t NZ_FLOATS = (size_t)TSTEPS * 5 * BATCH * NH;  // 65,536,000
  const size_t NEED = (OFF_NZ + NZ_FLOATS) * sizeof(float);

  if (ws_size >= NEED) {
    float* W = (float*)d_ws;
    pack_w<<<dim3(NH * NH / 256), dim3(256), 0, stream>>>(pred0, W + OFF_PRED0, NH, 0);
    pack_w<<<dim3(NH * NH / 256), dim3(256), 0, stream>>>(pred1, W + OFF_PRED1, NH, 0);
    pack_w<<<dim3(NH * NH / 256), dim3(256), 0, stream>>>(p2r0,  W + OFF_P2R0,  NH, 0);
    pack_w<<<dim3(NH * NH / 256), dim3(256), 0, stream>>>(rec0,  W + OFF_REC0,  NH, 1);
    pack_w<<<dim3(NS * NH / 256), dim3(256), 0, stream>>>(ff0,   W + OFF_FF0,   NS, 0);
    pack_w<<<dim3(NH * NH / 256), dim3(256), 0, stream>>>(p2r1,  W + OFF_P2R1,  NH, 0);
    pack_w<<<dim3(NH * NH / 256), dim3(256), 0, stream>>>(ff1,   W + OFF_FF1,   NH, 0);
    pack_w<<<dim3(NH * NH / 256), dim3(256), 0, stream>>>(rec1,  W + OFF_REC1,  NH, 1);
    pack_w<<<dim3(NH * NH / 256), dim3(256), 0, stream>>>(ff2,   W + OFF_FF2,   NH, 0);
    pack_w<<<dim3(NH * NH / 256), dim3(256), 0, stream>>>(rec2,  W + OFF_REC2,  NH, 1);
    gen_noise<<<dim3((unsigned)(NZ_FLOATS / 256)), dim3(256), 0, stream>>>(W + OFF_NZ);
    wm_fast3<<<dim3(BATCH), dim3(NH), 0, stream>>>(
        sensory,
        (const float4*)(W + OFF_PRED0), (const float4*)(W + OFF_PRED1),
        (const float4*)(W + OFF_P2R0),  (const float4*)(W + OFF_REC0),
        (const float4*)(W + OFF_FF0),   (const float4*)(W + OFF_P2R1),
        (const float4*)(W + OFF_FF1),   (const float4*)(W + OFF_REC1),
        (const float4*)(W + OFF_FF2),   (const float4*)(W + OFF_REC2),
        W + OFF_NZ, out);
  } else {
    wm_kernel_mono<<<dim3(BATCH), dim3(NH), 0, stream>>>(
        sensory, ff0, ff1, ff2, rec0, rec1, rec2,
        pred0, pred1, p2r0, p2r1, out);
  }
}

// Round 10
// 4554.195 us; speedup vs baseline: 11.1871x; 11.1871x over previous
//
#include <hip/hip_runtime.h>
#include <stdint.h>

#define TSTEPS 100
#define BATCH  512
#define NH     256
#define NS     128

__device__ __forceinline__ uint32_t rotl32(uint32_t x, int r) {
  return (x << r) | (x >> (32 - r));
}

// Threefry-2x32-20, exactly as jax/_src/prng.py
__device__ __forceinline__ void tf2x32(uint32_t k0, uint32_t k1,
                                       uint32_t c0, uint32_t c1,
                                       uint32_t& o0, uint32_t& o1) {
  const uint32_t ks2 = k0 ^ k1 ^ 0x1BD11BDAu;
  uint32_t x0 = c0 + k0, x1 = c1 + k1;
#define TFR(r) { x0 += x1; x1 = rotl32(x1, r); x1 ^= x0; }
  TFR(13) TFR(15) TFR(26) TFR(6)
  x0 += k1;  x1 += ks2 + 1u;
  TFR(17) TFR(29) TFR(16) TFR(24)
  x0 += ks2; x1 += k0 + 2u;
  TFR(13) TFR(15) TFR(26) TFR(6)
  x0 += k0;  x1 += k1 + 3u;
  TFR(17) TFR(29) TFR(16) TFR(24)
  x0 += k1;  x1 += ks2 + 4u;
  TFR(13) TFR(15) TFR(26) TFR(6)
  x0 += ks2; x1 += k0 + 5u;
#undef TFR
  o0 = x0; o1 = x1;
}

// XLA:CPU GenerateVF32Log (Cephes port, FMA form). Inputs in (0,1], normal.
__device__ __forceinline__ float xla_vf32_log(float a) {
  uint32_t bits = __float_as_uint(a);
  float e = __fadd_rn((float)((int)(bits >> 23) - 127), 1.0f);
  float x = __uint_as_float((bits & 0x007FFFFFu) | 0x3F000000u);
  const bool mask = x < 0.707106781186547524f;
  float tmp = mask ? x : 0.0f;
  x = __fsub_rn(x, 1.0f);
  e = mask ? __fsub_rn(e, 1.0f) : e;
  x = __fadd_rn(x, tmp);
  float z = __fmul_rn(x, x);
  float y = 7.0376836292e-2f;
  y = __fmaf_rn(y, x, -1.1514610310e-1f);
  y = __fmaf_rn(y, x, 1.1676998740e-1f);
  y = __fmaf_rn(y, x, -1.2420140846e-1f);
  y = __fmaf_rn(y, x, 1.4249322787e-1f);
  y = __fmaf_rn(y, x, -1.6668057665e-1f);
  y = __fmaf_rn(y, x, 2.0000714765e-1f);
  y = __fmaf_rn(y, x, -2.4999993993e-1f);
  y = __fmaf_rn(y, x, 3.3333331174e-1f);
  y = __fmul_rn(y, x);
  y = __fmul_rn(y, z);
  y = __fmaf_rn(e, -2.12194440e-4f, y);
  y = __fmaf_rn(-0.5f, z, y);
  x = __fadd_rn(x, y);
  x = __fmaf_rn(e, 0.693359375f, x);
  return x;
}

// sqrt(2)*erfinv(u): chlo erf_inv f32 (Giles) + EmitLog1p, FMA-contracted.
__device__ __forceinline__ float xla_sqrt2_erfinv(float u) {
  float nxx = -__fmul_rn(u, u);
  float w;
  if (fabsf(nxx) < 1e-4f) {
    w = -__fmul_rn(__fmaf_rn(-0.5f, nxx, 1.0f), nxx);
  } else {
    w = -xla_vf32_log(__fadd_rn(nxx, 1.0f));
  }
  float p;
  if (w < 5.0f) {
    float t = __fsub_rn(w, 2.5f);
    p = 2.81022636e-08f;
    p = __fmaf_rn(p, t, 3.43273939e-07f);
    p = __fmaf_rn(p, t, -3.5233877e-06f);
    p = __fmaf_rn(p, t, -4.39150654e-06f);
    p = __fmaf_rn(p, t, 0.00021858087f);
    p = __fmaf_rn(p, t, -0.00125372503f);
    p = __fmaf_rn(p, t, -0.00417768164f);
    p = __fmaf_rn(p, t, 0.246640727f);
    p = __fmaf_rn(p, t, 1.50140941f);
  } else {
    float t = __fsub_rn(__fsqrt_rn(w), 3.0f);
    p = -0.000200214257f;
    p = __fmaf_rn(p, t, 0.000100950558f);
    p = __fmaf_rn(p, t, 0.00134934322f);
    p = __fmaf_rn(p, t, -0.00367342844f);
    p = __fmaf_rn(p, t, 0.00573950773f);
    p = __fmaf_rn(p, t, -0.0076224613f);
    p = __fmaf_rn(p, t, 0.00943887047f);
    p = __fmaf_rn(p, t, 1.00167406f);
    p = __fmaf_rn(p, t, 2.83297682f);
  }
  return __fmul_rn((float)1.4142135623730951, __fmul_rn(p, u));
}

// jax.random.normal element j under key (k0,k1), threefry-partitionable.
__device__ __forceinline__ float jax_normal(uint32_t k0, uint32_t k1, uint32_t j) {
  uint32_t o0, o1;
  tf2x32(k0, k1, 0u, j, o0, o1);
  const uint32_t bits = o0 ^ o1;
  float f = __fsub_rn(__uint_as_float((bits >> 9) | 0x3f800000u), 1.0f);
  const float LO = -0.99999994f;
  float u = __fmaf_rn(f, 2.0f, LO);
  u = fmaxf(LO, u);
  return xla_sqrt2_erfinv(u);
}

// Pack W[K][256] -> P[k/4][n][4]; optionally zero diagonal (rec masks).
__global__ void pack_w(const float* __restrict__ src, float* __restrict__ dst,
                       int K, int zero_diag) {
  int tid = blockIdx.x * 256 + threadIdx.x;
  if (tid >= K * NH) return;
  int k = tid >> 8, n = tid & 255;
  float v = src[tid];
  if (zero_diag && k == n) v = 0.f;
  dst[(((k >> 2) * NH) + n) * 4 + (k & 3)] = v;
}

// Precompute all scaled noise draws: NZ[((t*5+d)*BATCH+b)*NH+n].
__global__ __launch_bounds__(256)
void gen_noise(float* __restrict__ NZ) {
  uint32_t idx = blockIdx.x * 256u + threadIdx.x;
  uint32_t j = idx & 131071u;          // b*NH + n
  uint32_t td = idx >> 17;             // t*5 + d  (< 500)
  uint32_t t = td / 5u, d = td - 5u * t;
  uint32_t fk0, fk1, k0, k1;
  tf2x32(0u, 42u, 0u, t, fk0, fk1);
  tf2x32(fk0, fk1, 0u, d, k0, k1);
  float z = jax_normal(k0, k1, j);
  float scale = (d >= 3u) ? 0.01f : 0.02f;
  NZ[idx] = __fmul_rn(scale, z);
}

// ============ dense k-ascending dot segments (verified R6 chains) ============
__device__ __forceinline__ void dot1_seg(const float4* __restrict__ P0,
                                         const float* __restrict__ A0,
                                         int n, int k4b, int k4e, float& r0) {
  float a0 = r0;
  #pragma unroll 8
  for (int k4 = k4b; k4 < k4e; ++k4) {
    float4 w0 = P0[k4 * NH + n];
    float4 x0 = *reinterpret_cast<const float4*>(A0 + 4 * k4);
    a0 = __fmaf_rn(x0.x, w0.x, a0); a0 = __fmaf_rn(x0.y, w0.y, a0);
    a0 = __fmaf_rn(x0.z, w0.z, a0); a0 = __fmaf_rn(x0.w, w0.w, a0);
  }
  r0 = a0;
}

__device__ __forceinline__ void dot2_seg(const float4* __restrict__ P0,
                                         const float* __restrict__ A0,
                                         const float4* __restrict__ P1,
                                         const float* __restrict__ A1,
                                         int n, int k4b, int k4e,
                                         float& r0, float& r1) {
  float a0 = r0, a1 = r1;
  #pragma unroll 8
  for (int k4 = k4b; k4 < k4e; ++k4) {
    float4 w0 = P0[k4 * NH + n];
    float4 w1 = P1[k4 * NH + n];
    float4 x0 = *reinterpret_cast<const float4*>(A0 + 4 * k4);
    float4 x1 = *reinterpret_cast<const float4*>(A1 + 4 * k4);
    a0 = __fmaf_rn(x0.x, w0.x, a0); a0 = __fmaf_rn(x0.y, w0.y, a0);
    a0 = __fmaf_rn(x0.z, w0.z, a0); a0 = __fmaf_rn(x0.w, w0.w, a0);
    a1 = __fmaf_rn(x1.x, w1.x, a1); a1 = __fmaf_rn(x1.y, w1.y, a1);
    a1 = __fmaf_rn(x1.z, w1.z, a1); a1 = __fmaf_rn(x1.w, w1.w, a1);
  }
  r0 = a0; r1 = a1;
}

__device__ __forceinline__ void dot3_seg(const float4* __restrict__ P0,
                                         const float* __restrict__ A0,
                                         const float4* __restrict__ P1,
                                         const float* __restrict__ A1,
                                         const float4* __restrict__ P2,
                                         const float* __restrict__ A2,
                                         int n, int k4b, int k4e,
                                         float& r0, float& r1, float& r2) {
  float a0 = r0, a1 = r1, a2 = r2;
  #pragma unroll 4
  for (int k4 = k4b; k4 < k4e; ++k4) {
    float4 w0 = P0[k4 * NH + n];
    float4 w1 = P1[k4 * NH + n];
    float4 w2 = P2[k4 * NH + n];
    float4 x0 = *reinterpret_cast<const float4*>(A0 + 4 * k4);
    float4 x1 = *reinterpret_cast<const float4*>(A1 + 4 * k4);
    float4 x2 = *reinterpret_cast<const float4*>(A2 + 4 * k4);
    a0 = __fmaf_rn(x0.x, w0.x, a0); a0 = __fmaf_rn(x0.y, w0.y, a0);
    a0 = __fmaf_rn(x0.z, w0.z, a0); a0 = __fmaf_rn(x0.w, w0.w, a0);
    a1 = __fmaf_rn(x1.x, w1.x, a1); a1 = __fmaf_rn(x1.y, w1.y, a1);
    a1 = __fmaf_rn(x1.z, w1.z, a1); a1 = __fmaf_rn(x1.w, w1.w, a1);
    a2 = __fmaf_rn(x2.x, w2.x, a2); a2 = __fmaf_rn(x2.y, w2.y, a2);
    a2 = __fmaf_rn(x2.z, w2.z, a2); a2 = __fmaf_rn(x2.w, w2.w, a2);
  }
  r0 = a0; r1 = a1; r2 = a2;
}

// ============ main: 2 rows/block, 512 threads, lane-pair weight sharing ======
// tid = n*2 + r: adjacent lanes read the SAME weight address (merged by the
// wave coalescer -> 512B unique bytes per wave-load, half of R6's per-CU L2
// traffic) while each thread still computes ONE row's chains (R6-identical).
__global__ __launch_bounds__(512)
void wm_fast4(const float* __restrict__ sensory,
              const float4* __restrict__ pred0p, const float4* __restrict__ pred1p,
              const float4* __restrict__ p2r0p,  const float4* __restrict__ rec0p,
              const float4* __restrict__ ff0p,   const float4* __restrict__ p2r1p,
              const float4* __restrict__ ff1p,   const float4* __restrict__ rec1p,
              const float4* __restrict__ ff2p,   const float4* __restrict__ rec2p,
              const float* __restrict__ NZ,
              float* __restrict__ out) {
  const int tid = threadIdx.x;
  const int n = tid >> 1;          // neuron
  const int r = tid & 1;           // row within block
  const int b = blockIdx.x * 2 + r;

  __shared__ __align__(16) float last[2][3][2][NH];
  __shared__ __align__(16) float psp0[2][NH];
  __shared__ __align__(16) float psp1[2][NH];
  __shared__ __align__(16) float sens[2][NS];
  __shared__ __align__(16) float errsq[3][2][NH];
  __shared__ float evsum[3][2];

  #pragma unroll
  for (int i = 0; i < 3; ++i) {
    last[0][i][r][n] = 0.f;
    last[1][i][r][n] = 0.f;
  }

  float v0 = 0.f, v1 = 0.f, v2 = 0.f, pv0 = 0.f, pv1 = 0.f;
  float prec0 = 1.f, prec1 = 1.f, prec2 = 1.f;
  const float DM = (float)0.951229424500714009;  // f32(exp(-1/20))
  const float DP = (float)0.980198673306755250;  // f32(exp(-1/50))

  __syncthreads();

  for (int t = 0; t < TSTEPS; ++t) {
    const int p = t & 1, q = p ^ 1;
    const size_t nb = ((size_t)t * 5 * BATCH + b) * NH + n;  // draw 0 offset

    // ---- A: sens load + fused pred-LIF 0 & 1 ----
    if (tid < 2 * NS) {
      int rr = tid >> 7, kk = tid & 127;
      sens[rr][kk] = sensory[((size_t)t * BATCH + blockIdx.x * 2 + rr) * NS + kk];
    }
    {
      float pn0 = NZ[nb + (size_t)3 * BATCH * NH];
      float pn1 = NZ[nb + (size_t)4 * BATCH * NH];
      float acc0 = 0.f, acc1 = 0.f;
      dot2_seg(pred0p, last[p][1][r], pred1p, last[p][2][r], n, 0, 64, acc0, acc1);
      pv0 = __fadd_rn(__fmaf_rn(DP, pv0, acc0), pn0);
      bool s0 = (pv0 >= 1.0f);
      psp0[r][n] = s0 ? 1.f : 0.f;
      pv0 = s0 ? 0.f : pv0;
      pv1 = __fadd_rn(__fmaf_rn(DP, pv1, acc1), pn1);
      bool s1 = (pv1 >= 1.0f);
      psp1[r][n] = s1 ? 1.f : 0.f;
      pv1 = s1 ? 0.f : pv1;
    }
    __syncthreads();

    // ---- B: layer 0 ----
    {
      float noi = NZ[nb];
      float pr = 0.f, rc = 0.f, inp = 0.f;
      dot3_seg(p2r0p, psp0[r], rec0p, last[p][0][r], ff0p, sens[r], n, 0, 32,
               pr, rc, inp);
      dot2_seg(p2r0p, psp0[r], rec0p, last[p][0][r], n, 32, 64, pr, rc);
      float err = __fsub_rn(inp, pr);
      out[(((size_t)t * 3 + 0) * BATCH + b) * NH + n] = err;
      errsq[0][r][n] = __fmul_rn(err, err);
      float m1  = __fmul_rn(err, 0.5f);
      float tot = __fadd_rn(__fmaf_rn(m1, prec0, pr), rc);
      v0 = __fadd_rn(__fmaf_rn(DM, v0, tot), noi);
      bool s = (v0 >= 1.0f);
      last[q][0][r][n] = s ? 1.f : 0.f;
      v0 = s ? 0.f : v0;
    }
    __syncthreads();

    // ---- D: layer 1 (input: NEW layer-0 spikes; pred from psp1) ----
    {
      float noi = NZ[nb + (size_t)1 * BATCH * NH];
      float pr = 0.f, inp = 0.f, rc = 0.f;
      dot3_seg(p2r1p, psp1[r], ff1p, last[q][0][r], rec1p, last[p][1][r],
               n, 0, 64, pr, inp, rc);
      float err = __fsub_rn(inp, pr);
      out[(((size_t)t * 3 + 1) * BATCH + b) * NH + n] = err;
      errsq[1][r][n] = __fmul_rn(err, err);
      float m1  = __fmul_rn(err, 0.5f);
      float tot = __fadd_rn(__fmaf_rn(m1, prec1, pr), rc);
      v1 = __fadd_rn(__fmaf_rn(DM, v1, tot), noi);
      bool s = (v1 >= 1.0f);
      last[q][1][r][n] = s ? 1.f : 0.f;
      v1 = s ? 0.f : v1;
    }
    __syncthreads();

    // ---- E: layer 2 (no prediction) ----
    {
      float noi = NZ[nb + (size_t)2 * BATCH * NH];
      float inp = 0.f, rc = 0.f;
      dot2_seg(ff2p, last[q][1][r], rec2p, last[p][2][r], n, 0, 64, inp, rc);
      float err = inp;
      out[(((size_t)t * 3 + 2) * BATCH + b) * NH + n] = err;
      errsq[2][r][n] = __fmul_rn(err, err);
      float m1  = __fmul_rn(err, 0.5f);
      float tot = __fadd_rn(__fmaf_rn(m1, prec2, 0.0f), rc);
      v2 = __fadd_rn(__fmaf_rn(DM, v2, tot), noi);
      bool s = (v2 >= 1.0f);
      last[q][2][r][n] = s ? 1.f : 0.f;
      v2 = s ? 0.f : v2;
    }
    __syncthreads();

    // ---- F: strict sequential err^2 sums: 6 chains on 6 lanes ----
    if (tid < 6) {
      const int l = tid >> 1, rr = tid & 1;
      const float4* s4 = reinterpret_cast<const float4*>(errsq[l][rr]);
      float acc = 0.f;
      #pragma unroll 16
      for (int k4 = 0; k4 < 64; ++k4) {
        float4 v = s4[k4];
        acc = __fadd_rn(acc, v.x); acc = __fadd_rn(acc, v.y);
        acc = __fadd_rn(acc, v.z); acc = __fadd_rn(acc, v.w);
      }
      evsum[l][rr] = acc;
    }
    __syncthreads();

    // ---- G: precision EMA (per thread, own row) ----
    {
      float ev0 = __fadd_rn(__fmul_rn(evsum[0][r], 0.00390625f), 1e-6f);
      float ev1 = __fadd_rn(__fmul_rn(evsum[1][r], 0.00390625f), 1e-6f);
      float ev2 = __fadd_rn(__fmul_rn(evsum[2][r], 0.00390625f), 1e-6f);
      prec0 = __fmaf_rn(0.98f, prec0, __fmul_rn(0.02f, 1.0f / ev0));
      prec1 = __fmaf_rn(0.98f, prec1, __fmul_rn(0.02f, 1.0f / ev1));
      prec2 = __fmaf_rn(0.98f, prec2, __fmul_rn(0.02f, 1.0f / ev2));
    }
  }
}

// ======================= fallback (verified R5 kernel) =======================
__device__ __forceinline__ float dot_lds(const float* __restrict__ a,
                                         const float* __restrict__ W,
                                         int n, int K) {
  float acc = 0.f;
  #pragma unroll 8
  for (int k = 0; k < K; ++k)
    acc = __fmaf_rn(a[k], W[k * NH + n], acc);
  return acc;
}

__device__ __forceinline__ float dot_rec(const float* __restrict__ a,
                                         const float* __restrict__ W, int n) {
  float acc = 0.f;
  #pragma unroll 8
  for (int k = 0; k < NH; ++k) {
    float w = (k == n) ? 0.f : W[k * NH + n];
    acc = __fmaf_rn(a[k], w, acc);
  }
  return acc;
}

__global__ __launch_bounds__(NH)
void wm_kernel_mono(const float* __restrict__ sensory,
                    const float* __restrict__ ff0, const float* __restrict__ ff1,
                    const float* __restrict__ ff2,
                    const float* __restrict__ rec0, const float* __restrict__ rec1,
                    const float* __restrict__ rec2,
                    const float* __restrict__ pred0, const float* __restrict__ pred1,
                    const float* __restrict__ p2r0, const float* __restrict__ p2r1,
                    float* __restrict__ out) {
  const int b = blockIdx.x;
  const int n = threadIdx.x;

  __shared__ float last[2][3][NH];
  __shared__ float psp[NH];
  __shared__ float sens[NS];
  __shared__ float errsq[3][NH];
  __shared__ float evsum[3];
  __shared__ uint32_t keys[TSTEPS][5][2];

  if (n < TSTEPS) {
    uint32_t fk0, fk1;
    tf2x32(0u, 42u, 0u, (uint32_t)n, fk0, fk1);
    #pragma unroll
    for (int i = 0; i < 5; ++i) {
      uint32_t s0, s1;
      tf2x32(fk0, fk1, 0u, (uint32_t)i, s0, s1);
      keys[n][i][0] = s0; keys[n][i][1] = s1;
    }
  }
  for (int i = 0; i < 3; ++i) { last[0][i][n] = 0.f; last[1][i][n] = 0.f; }

  float v0 = 0.f, v1 = 0.f, v2 = 0.f, pv0 = 0.f, pv1 = 0.f;
  float prec0 = 1.f, prec1 = 1.f, prec2 = 1.f;
  const float DM = (float)0.951229424500714009;
  const float DP = (float)0.980198673306755250;
  const uint32_t j = (uint32_t)(b * NH + n);

  __syncthreads();

  for (int t = 0; t < TSTEPS; ++t) {
    const int p = t & 1, q = p ^ 1;

    if (n < NS) sens[n] = sensory[((size_t)t * BATCH + b) * NS + n];
    {
      float acc = dot_lds(last[p][1], pred0, n, NH);
      float pn = __fmul_rn(0.01f, jax_normal(keys[t][3][0], keys[t][3][1], j));
      pv0 = __fadd_rn(__fmaf_rn(DP, pv0, acc), pn);
      bool s = (pv0 >= 1.0f);
      psp[n] = s ? 1.f : 0.f;
      pv0 = s ? 0.f : pv0;
    }
    __syncthreads();

    {
      float pr  = dot_lds(psp, p2r0, n, NH);
      float inp = dot_lds(sens, ff0, n, NS);
      float rc  = dot_rec(last[p][0], rec0, n);
      float err = __fsub_rn(inp, pr);
      out[(((size_t)t * 3 + 0) * BATCH + b) * NH + n] = err;
      errsq[0][n] = __fmul_rn(err, err);
      float m1  = __fmul_rn(err, 0.5f);
      float tot = __fadd_rn(__fmaf_rn(m1, prec0, pr), rc);
      float noi = __fmul_rn(0.02f, jax_normal(keys[t][0][0], keys[t][0][1], j));
      v0 = __fadd_rn(__fmaf_rn(DM, v0, tot), noi);
      bool s = (v0 >= 1.0f);
      last[q][0][n] = s ? 1.f : 0.f;
      v0 = s ? 0.f : v0;
    }
    __syncthreads();

    {
      float acc = dot_lds(last[p][2], pred1, n, NH);
      float pn = __fmul_rn(0.01f, jax_normal(keys[t][4][0], keys[t][4][1], j));
      pv1 = __fadd_rn(__fmaf_rn(DP, pv1, acc), pn);
      bool s = (pv1 >= 1.0f);
      psp[n] = s ? 1.f : 0.f;
      pv1 = s ? 0.f : pv1;
    }
    __syncthreads();

    {
      float pr  = dot_lds(psp, p2r1, n, NH);
      float inp = dot_lds(last[q][0], ff1, n, NH);
      float rc  = dot_rec(last[p][1], rec1, n);
      float err = __fsub_rn(inp, pr);
      out[(((size_t)t * 3 + 1) * BATCH + b) * NH + n] = err;
      errsq[1][n] = __fmul_rn(err, err);
      float m1  = __fmul_rn(err, 0.5f);
      float tot = __fadd_rn(__fmaf_rn(m1, prec1, pr), rc);
      float noi = __fmul_rn(0.02f, jax_normal(keys[t][1][0], keys[t][1][1], j));
      v1 = __fadd_rn(__fmaf_rn(DM, v1, tot), noi);
      bool s = (v1 >= 1.0f);
      last[q][1][n] = s ? 1.f : 0.f;
      v1 = s ? 0.f : v1;
    }
    __syncthreads();

    {
      float inp = dot_lds(last[q][1], ff2, n, NH);
      float rc  = dot_rec(last[p][2], rec2, n);
      float err = inp;
      out[(((size_t)t * 3 + 2) * BATCH + b) * NH + n] = err;
      errsq[2][n] = __fmul_rn(err, err);
      float m1  = __fmul_rn(err, 0.5f);
      float tot = __fadd_rn(__fmaf_rn(m1, prec2, 0.0f), rc);
      float noi = __fmul_rn(0.02f, jax_normal(keys[t][2][0], keys[t][2][1], j));
      v2 = __fadd_rn(__fmaf_rn(DM, v2, tot), noi);
      bool s = (v2 >= 1.0f);
      last[q][2][n] = s ? 1.f : 0.f;
      v2 = s ? 0.f : v2;
    }
    __syncthreads();

    if (((n & 63) == 0) && n < 192) {
      const float* s = errsq[n >> 6];
      float acc = 0.f;
      #pragma unroll 32
      for (int k = 0; k < NH; ++k) acc = __fadd_rn(acc, s[k]);
      evsum[n >> 6] = acc;
    }
    __syncthreads();

    {
      float ev0 = __fadd_rn(__fmul_rn(evsum[0], 0.00390625f), 1e-6f);
      float ev1 = __fadd_rn(__fmul_rn(evsum[1], 0.00390625f), 1e-6f);
      float ev2 = __fadd_rn(__fmul_rn(evsum[2], 0.00390625f), 1e-6f);
      prec0 = __fmaf_rn(0.98f, prec0, __fmul_rn(0.02f, 1.0f / ev0));
      prec1 = __fmaf_rn(0.98f, prec1, __fmul_rn(0.02f, 1.0f / ev1));
      prec2 = __fmaf_rn(0.98f, prec2, __fmul_rn(0.02f, 1.0f / ev2));
    }
  }
}

extern "C" void kernel_launch(void* const* d_in, const int* in_sizes, int n_in,
                              void* d_out, int out_size, void* d_ws, size_t ws_size,
                              hipStream_t stream) {
  (void)in_sizes; (void)n_in; (void)out_size;
  const float* sensory = (const float*)d_in[0];
  const float* ff0  = (const float*)d_in[1];
  const float* ff1  = (const float*)d_in[2];
  const float* ff2  = (const float*)d_in[3];
  const float* rec0 = (const float*)d_in[4];
  const float* rec1 = (const float*)d_in[5];
  const float* rec2 = (const float*)d_in[6];
  const float* pred0 = (const float*)d_in[7];
  const float* pred1 = (const float*)d_in[8];
  const float* p2r0 = (const float*)d_in[9];
  const float* p2r1 = (const float*)d_in[10];
  float* out = (float*)d_out;

  // ws layout (floats): packed weights then noise.
  const size_t OFF_PRED0 = 0, OFF_PRED1 = 65536, OFF_P2R0 = 131072,
               OFF_REC0 = 196608, OFF_FF0 = 262144, OFF_P2R1 = 294912,
               OFF_FF1 = 360448, OFF_REC1 = 425984, OFF_FF2 = 491520,
               OFF_REC2 = 557056, OFF_NZ = 655360;
  const size_t NZ_FLOATS = (size_t)TSTEPS * 5 * BATCH * NH;  // 65,536,000
  const size_t NEED = (OFF_NZ + NZ_FLOATS) * sizeof(float);

  if (ws_size >= NEED) {
    float* W = (float*)d_ws;
    pack_w<<<dim3(NH * NH / 256), dim3(256), 0, stream>>>(pred0, W + OFF_PRED0, NH, 0);
    pack_w<<<dim3(NH * NH / 256), dim3(256), 0, stream>>>(pred1, W + OFF_PRED1, NH, 0);
    pack_w<<<dim3(NH * NH / 256), dim3(256), 0, stream>>>(p2r0,  W + OFF_P2R0,  NH, 0);
    pack_w<<<dim3(NH * NH / 256), dim3(256), 0, stream>>>(rec0,  W + OFF_REC0,  NH, 1);
    pack_w<<<dim3(NS * NH / 256), dim3(256), 0, stream>>>(ff0,   W + OFF_FF0,   NS, 0);
    pack_w<<<dim3(NH * NH / 256), dim3(256), 0, stream>>>(p2r1,  W + OFF_P2R1,  NH, 0);
    pack_w<<<dim3(NH * NH / 256), dim3(256), 0, stream>>>(ff1,   W + OFF_FF1,   NH, 0);
    pack_w<<<dim3(NH * NH / 256), dim3(256), 0, stream>>>(rec1,  W + OFF_REC1,  NH, 1);
    pack_w<<<dim3(NH * NH / 256), dim3(256), 0, stream>>>(ff2,   W + OFF_FF2,   NH, 0);
    pack_w<<<dim3(NH * NH / 256), dim3(256), 0, stream>>>(rec2,  W + OFF_REC2,  NH, 1);
    gen_noise<<<dim3((unsigned)(NZ_FLOATS / 256)), dim3(256), 0, stream>>>(W + OFF_NZ);
    wm_fast4<<<dim3(BATCH / 2), dim3(512), 0, stream>>>(
        sensory,
        (const float4*)(W + OFF_PRED0), (const float4*)(W + OFF_PRED1),
        (const float4*)(W + OFF_P2R0),  (const float4*)(W + OFF_REC0),
        (const float4*)(W + OFF_FF0),   (const float4*)(W + OFF_P2R1),
        (const float4*)(W + OFF_FF1),   (const float4*)(W + OFF_REC1),
        (const float4*)(W + OFF_FF2),   (const float4*)(W + OFF_REC2),
        W + OFF_NZ, out);
  } else {
    wm_kernel_mono<<<dim3(BATCH), dim3(NH), 0, stream>>>(
        sensory, ff0, ff1, ff2, rec0, rec1, rec2,
        pred0, pred1, p2r0, p2r1, out);
  }
}